// Round 2
// baseline (5578.630 us; speedup 1.0000x reference)
//
#include <hip/hip_runtime.h>

// Persistent 2-layer LSTM, T=512, B=64, H=512. fp32 in/out, bf16 MFMA.
// One kernel for all timesteps; blocks 0..31 = layer0 domain, 32..63 = layer1.
// Weights live in VGPRs (loaded once); h-state via 8-slot global rings with
// device-scope release/acquire counters; c-state in registers.

#define T_SEQ 512
#define BATCH 64
#define HID   512
#define NRING 8

typedef short s16x8 __attribute__((ext_vector_type(8)));
typedef float f32x4 __attribute__((ext_vector_type(4)));

__device__ __forceinline__ short f2bf(float f) {
    unsigned u = __builtin_bit_cast(unsigned, f);
    unsigned r = (u + 0x7fffu + ((u >> 16) & 1u)) >> 16;   // RNE
    return (short)r;
}
__device__ __forceinline__ float sigf(float x) { return 1.0f / (1.0f + __expf(-x)); }
__device__ __forceinline__ float tanhff(float x) { return 2.0f * sigf(2.0f * x) - 1.0f; }

// ---- setup: cast x (fp32) -> bf16 ----
__global__ __launch_bounds__(256) void xcast_kernel(const float* __restrict__ x,
                                                    short* __restrict__ xb) {
    int i = (blockIdx.x * 256 + threadIdx.x) * 8;
    float4 a = *(const float4*)(x + i);
    float4 b = *(const float4*)(x + i + 4);
    s16x8 v;
    v[0]=f2bf(a.x); v[1]=f2bf(a.y); v[2]=f2bf(a.z); v[3]=f2bf(a.w);
    v[4]=f2bf(b.x); v[5]=f2bf(b.y); v[6]=f2bf(b.z); v[7]=f2bf(b.w);
    *(s16x8*)(xb + i) = v;
}

// ---- setup: pack weights, layout [l][bb][wave][gate][kk][lane][8] bf16 ----
// wave w owns K-slice [256w, 256w+256); per (g,kk) a bfrag:
//   B[k][n]: k = (w*8+kk)*32 + (lane>>4)*8 + i, n = lane&15,
//   col j' = g*512 + bb*16 + n; k<512 -> Wxh[l][j'][k], else Whh[l][j'][k-512].
__global__ __launch_bounds__(256) void wpack_kernel(const float* __restrict__ Wxh,
                                                    const float* __restrict__ Whh,
                                                    short* __restrict__ wp) {
    int fg = blockIdx.x * 256 + threadIdx.x;        // [0, 524288)
    int lane = fg & 63;
    int kk   = (fg >> 6)  & 7;
    int g    = (fg >> 9)  & 3;
    int w    = (fg >> 11) & 3;
    int bb   = (fg >> 13) & 31;
    int l    = (fg >> 18) & 1;
    int k0 = (w * 8 + kk) * 32 + (lane >> 4) * 8;
    int jp = g * 512 + bb * 16 + (lane & 15);
    const float* src = (k0 < 512) ? (Wxh + ((size_t)(l * 2048 + jp) * 512 + k0))
                                  : (Whh + ((size_t)(l * 2048 + jp) * 512 + (k0 - 512)));
    float4 a = *(const float4*)src;
    float4 b = *(const float4*)(src + 4);
    s16x8 v;
    v[0]=f2bf(a.x); v[1]=f2bf(a.y); v[2]=f2bf(a.z); v[3]=f2bf(a.w);
    v[4]=f2bf(b.x); v[5]=f2bf(b.y); v[6]=f2bf(b.z); v[7]=f2bf(b.w);
    *(s16x8*)(wp + (size_t)fg * 8) = v;
}

__device__ __forceinline__ unsigned ld_ctr(const unsigned* p) {
    return __hip_atomic_load(p, __ATOMIC_ACQUIRE, __HIP_MEMORY_SCOPE_AGENT);
}

__global__ __launch_bounds__(256, 1) void lstm_persist(
    const short* __restrict__ xb,    // [T][64][512] bf16
    const short* __restrict__ wp,    // packed weights
    short* __restrict__ h0r,         // [NRING][64][512] bf16 ring (slot s holds h0[s-1])
    short* __restrict__ h1r,         // [NRING][64][512] bf16 ring
    const float* __restrict__ bxh,   // [2][2048]
    const float* __restrict__ bhh,   // [2][2048]
    float* __restrict__ out,         // T*B*H | hT[2,B,H] | cT[2,B,H]
    unsigned* ctr0, unsigned* ctr1) {

    const int l    = blockIdx.x >> 5;
    const int bb   = blockIdx.x & 31;
    const int tid  = threadIdx.x;
    const int wv   = tid >> 6;
    const int lane = tid & 63;

    __shared__ float red[4 * 4 * 64 * 16];   // [wave][gate][64 rows][16 n] = 64 KB

    // ---- load weight slice into registers (once) ----
    s16x8 breg[4][8];                         // [gate][kk] -> 128 VGPRs
    {
        const short* wb = wp + (size_t)(blockIdx.x * 4 + wv) * 32 * 512 + lane * 8;
        #pragma unroll
        for (int g = 0; g < 4; ++g)
            #pragma unroll
            for (int kk = 0; kk < 8; ++kk)
                breg[g][kk] = *(const s16x8*)(wb + (g * 8 + kk) * 512);
    }

    // ---- per-thread epilogue constants ----
    const int n  = tid & 15;
    const int j  = bb * 16 + n;
    const int m0 = tid >> 4;
    float bsum[4];
    #pragma unroll
    for (int g = 0; g < 4; ++g)
        bsum[g] = bxh[l * 2048 + g * 512 + j] + bhh[l * 2048 + g * 512 + j];

    float creg[4] = {0.f, 0.f, 0.f, 0.f};    // c-state, lives here all 512 steps

    const int aoff = (lane & 15) * 512 + (wv & 1) * 256 + (lane >> 4) * 8;
    unsigned* myctr = (l == 0) ? ctr0 : ctr1;

    for (int t = 0; t < T_SEQ; ++t) {
        // ---- wait phase ----
        if (tid == 0) {
            unsigned tgt = 32u * (unsigned)t;                 // own domain: round t-1 done
            while (ld_ctr(myctr) < tgt) __builtin_amdgcn_s_sleep(1);
            if (l == 0) {
                if (t >= 8) {                                  // ring back-pressure vs l1
                    unsigned tg2 = 32u * (unsigned)(t - 7);
                    while (ld_ctr(ctr1) < tg2) __builtin_amdgcn_s_sleep(1);
                }
            } else {
                unsigned tg2 = 32u * (unsigned)(t + 1);        // h0[t] published
                while (ld_ctr(ctr0) < tg2) __builtin_amdgcn_s_sleep(1);
            }
            __threadfence();
        }
        __syncthreads();

        // ---- A-fragment loads (direct from global; wave wv owns K [256wv,256wv+256)) ----
        const short* ab;
        if (wv < 2) ab = (l == 0) ? (xb + (size_t)t * 32768)
                                  : (h0r + (size_t)((t + 1) & 7) * 32768);
        else        ab = (l == 0) ? (h0r + (size_t)(t & 7) * 32768)
                                  : (h1r + (size_t)(t & 7) * 32768);
        s16x8 af[8][4];                        // [kk][ms] -> 128 VGPRs
        #pragma unroll
        for (int kk = 0; kk < 8; ++kk)
            #pragma unroll
            for (int ms = 0; ms < 4; ++ms)
                af[kk][ms] = *(const s16x8*)(ab + aoff + ms * 8192 + kk * 32);

        // ---- MFMA: partial gates over this wave's K-slice ----
        f32x4 acc[4][4];                       // [gate][ms] -> 64 VGPRs
        #pragma unroll
        for (int g = 0; g < 4; ++g)
            #pragma unroll
            for (int ms = 0; ms < 4; ++ms)
                acc[g][ms] = (f32x4){0.f, 0.f, 0.f, 0.f};
        #pragma unroll
        for (int kk = 0; kk < 8; ++kk)
            #pragma unroll
            for (int g = 0; g < 4; ++g)
                #pragma unroll
                for (int ms = 0; ms < 4; ++ms)
                    acc[g][ms] = __builtin_amdgcn_mfma_f32_16x16x32_bf16(
                        af[kk][ms], breg[g][kk], acc[g][ms], 0, 0, 0);

        // ---- cross-wave K-reduction via LDS ----
        #pragma unroll
        for (int g = 0; g < 4; ++g)
            #pragma unroll
            for (int ms = 0; ms < 4; ++ms)
                #pragma unroll
                for (int q = 0; q < 4; ++q)
                    red[((wv * 4 + g) * 64 + ms * 16 + (lane >> 4) * 4 + q) * 16 + (lane & 15)]
                        = acc[g][ms][q];
        __syncthreads();

        // ---- elementwise LSTM cell + writes ----
        short* hring = (l == 0) ? h0r : h1r;
        #pragma unroll
        for (int q = 0; q < 4; ++q) {
            int m = m0 + 16 * q;
            float gv[4];
            #pragma unroll
            for (int g = 0; g < 4; ++g)
                gv[g] = red[((0 * 4 + g) * 64 + m) * 16 + n]
                      + red[((1 * 4 + g) * 64 + m) * 16 + n]
                      + red[((2 * 4 + g) * 64 + m) * 16 + n]
                      + red[((3 * 4 + g) * 64 + m) * 16 + n]
                      + bsum[g];
            float c_new = sigf(gv[1]) * creg[q] + sigf(gv[0]) * tanhff(gv[2]);
            float h = sigf(gv[3]) * tanhff(c_new);
            creg[q] = c_new;
            hring[(size_t)((t + 1) & 7) * 32768 + (size_t)m * 512 + j] = f2bf(h);
            if (l == 1) out[(size_t)t * 32768 + (size_t)m * 512 + j] = h;
            if (t == T_SEQ - 1) {
                size_t base = (size_t)T_SEQ * 32768;
                out[base + (size_t)(l * 64 + m) * 512 + j] = h;
                out[base + 65536 + (size_t)(l * 64 + m) * 512 + j] = c_new;
            }
        }

        // ---- publish ----
        __syncthreads();
        if (tid == 0) {
            __threadfence();
            __hip_atomic_fetch_add(myctr, 1u, __ATOMIC_RELEASE, __HIP_MEMORY_SCOPE_AGENT);
        }
    }
}

extern "C" void kernel_launch(void* const* d_in, const int* in_sizes, int n_in,
                              void* d_out, int out_size, void* d_ws, size_t ws_size,
                              hipStream_t stream) {
    const float* x   = (const float*)d_in[0];
    const float* Wxh = (const float*)d_in[1];
    const float* Whh = (const float*)d_in[2];
    const float* bxh = (const float*)d_in[3];
    const float* bhh = (const float*)d_in[4];
    float* out = (float*)d_out;

    char* ws = (char*)d_ws;
    short*    xb   = (short*)(ws);                      // 33,554,432 B
    short*    wpk  = (short*)(ws + 33554432);           //  8,388,608 B
    short*    h0r  = (short*)(ws + 41943040);           //    524,288 B
    short*    h1r  = (short*)(ws + 42467328);           //    524,288 B
    unsigned* ctr0 = (unsigned*)(ws + 42991616);
    unsigned* ctr1 = (unsigned*)(ws + 42991744);        // separate cache line

    // zero rings + counters (ws is re-poisoned 0xAA before every timed launch)
    hipMemsetAsync(ws + 41943040, 0, 1048832, stream);

    xcast_kernel<<<dim3(8192), dim3(256), 0, stream>>>(x, xb);
    wpack_kernel<<<dim3(2048), dim3(256), 0, stream>>>(Wxh, Whh, wpk);

    lstm_persist<<<dim3(64), dim3(256), 0, stream>>>(xb, wpk, h0r, h1r,
                                                     bxh, bhh, out, ctr0, ctr1);
}

// Round 3
// 4636.822 us; speedup vs baseline: 1.2031x; 1.2031x over previous
//
#include <hip/hip_runtime.h>

// Persistent 2-layer LSTM, T=512, B=64, H=512. fp32 in/out, bf16 MFMA.
// Blocks 0..31 = layer0, 32..63 = layer1. Weights in VGPRs. Cross-block
// h exchange via L3 (inline-asm sc0 sc1 loads/stores, NO cache-maintenance
// ops). Per-wave flag words (single-writer, plain sc1 stores) for sync.

#define T_SEQ 512

typedef short s16x8 __attribute__((ext_vector_type(8)));
typedef int   i32x4 __attribute__((ext_vector_type(4)));
typedef int   i32x2 __attribute__((ext_vector_type(2)));
typedef float f32x4 __attribute__((ext_vector_type(4)));

__device__ __forceinline__ short f2bf(float f) {
    unsigned u = __builtin_bit_cast(unsigned, f);
    unsigned r = (u + 0x7fffu + ((u >> 16) & 1u)) >> 16;   // RNE
    return (short)r;
}
__device__ __forceinline__ float sigf(float x) { return 1.0f / (1.0f + __expf(-x)); }
__device__ __forceinline__ float tanhff(float x) { return 2.0f * sigf(2.0f * x) - 1.0f; }

// ---- setup: cast x (fp32) -> bf16 ----
__global__ __launch_bounds__(256) void xcast_kernel(const float* __restrict__ x,
                                                    short* __restrict__ xb) {
    int i = (blockIdx.x * 256 + threadIdx.x) * 8;
    float4 a = *(const float4*)(x + i);
    float4 b = *(const float4*)(x + i + 4);
    s16x8 v;
    v[0]=f2bf(a.x); v[1]=f2bf(a.y); v[2]=f2bf(a.z); v[3]=f2bf(a.w);
    v[4]=f2bf(b.x); v[5]=f2bf(b.y); v[6]=f2bf(b.z); v[7]=f2bf(b.w);
    *(s16x8*)(xb + i) = v;
}

// ---- setup: pack weights [l][bb][w][g][kk0..7][lane][8] bf16 ----
// wave w: kk 0..3 -> input half, k = w*128 + kk*32 + (lane>>4)*8 (Wxh)
//         kk 4..7 -> recurrent half, same k formula (Whh)
// col j' = g*512 + bb*16 + (lane&15)
__global__ __launch_bounds__(256) void wpack_kernel(const float* __restrict__ Wxh,
                                                    const float* __restrict__ Whh,
                                                    short* __restrict__ wp) {
    int fg = blockIdx.x * 256 + threadIdx.x;        // [0, 524288)
    int lane = fg & 63;
    int kk   = (fg >> 6)  & 7;
    int g    = (fg >> 9)  & 3;
    int w    = (fg >> 11) & 3;
    int bb   = (fg >> 13) & 31;
    int l    = (fg >> 18) & 1;
    int ksrc = w * 128 + (kk & 3) * 32 + (lane >> 4) * 8;
    int jp   = g * 512 + bb * 16 + (lane & 15);
    const float* src = (kk < 4) ? (Wxh + ((size_t)(l * 2048 + jp) * 512 + ksrc))
                                : (Whh + ((size_t)(l * 2048 + jp) * 512 + ksrc));
    float4 a = *(const float4*)src;
    float4 b = *(const float4*)(src + 4);
    s16x8 v;
    v[0]=f2bf(a.x); v[1]=f2bf(a.y); v[2]=f2bf(a.z); v[3]=f2bf(a.w);
    v[4]=f2bf(b.x); v[5]=f2bf(b.y); v[6]=f2bf(b.z); v[7]=f2bf(b.w);
    *(s16x8*)(wp + (size_t)fg * 8) = v;
}

// ---- coherent (L3) 16-frag load: af[ms][kk], bypasses L1/L2, no inv ----
__device__ __forceinline__ void load16_c(i32x4 af[4][4], const short* base) {
    const short* a0 = base;
    const short* a1 = base + 8192;
    const short* a2 = base + 16384;
    const short* a3 = base + 24576;
    asm volatile(
        "global_load_dwordx4 %0, %16, off sc0 sc1\n\t"
        "global_load_dwordx4 %1, %16, off offset:64 sc0 sc1\n\t"
        "global_load_dwordx4 %2, %16, off offset:128 sc0 sc1\n\t"
        "global_load_dwordx4 %3, %16, off offset:192 sc0 sc1\n\t"
        "global_load_dwordx4 %4, %17, off sc0 sc1\n\t"
        "global_load_dwordx4 %5, %17, off offset:64 sc0 sc1\n\t"
        "global_load_dwordx4 %6, %17, off offset:128 sc0 sc1\n\t"
        "global_load_dwordx4 %7, %17, off offset:192 sc0 sc1\n\t"
        "global_load_dwordx4 %8, %18, off sc0 sc1\n\t"
        "global_load_dwordx4 %9, %18, off offset:64 sc0 sc1\n\t"
        "global_load_dwordx4 %10, %18, off offset:128 sc0 sc1\n\t"
        "global_load_dwordx4 %11, %18, off offset:192 sc0 sc1\n\t"
        "global_load_dwordx4 %12, %19, off sc0 sc1\n\t"
        "global_load_dwordx4 %13, %19, off offset:64 sc0 sc1\n\t"
        "global_load_dwordx4 %14, %19, off offset:128 sc0 sc1\n\t"
        "global_load_dwordx4 %15, %19, off offset:192 sc0 sc1\n\t"
        "s_waitcnt vmcnt(0)"
        : "=&v"(af[0][0]), "=&v"(af[0][1]), "=&v"(af[0][2]), "=&v"(af[0][3]),
          "=&v"(af[1][0]), "=&v"(af[1][1]), "=&v"(af[1][2]), "=&v"(af[1][3]),
          "=&v"(af[2][0]), "=&v"(af[2][1]), "=&v"(af[2][2]), "=&v"(af[2][3]),
          "=&v"(af[3][0]), "=&v"(af[3][1]), "=&v"(af[3][2]), "=&v"(af[3][3])
        : "v"(a0), "v"(a1), "v"(a2), "v"(a3)
        : "memory");
}

// ---- wait: all 128 per-wave flags of fa >= ta (and fb >= tb if tb>0) ----
__device__ __forceinline__ void waitf(const unsigned* fa, int ta,
                                      const unsigned* fb, int tb, int lane) {
    if (ta > 0) {
        int v0, v1;
        const unsigned* pa = fa + lane;
        do {
            asm volatile("global_load_dword %0, %2, off sc0 sc1\n\t"
                         "global_load_dword %1, %3, off sc0 sc1\n\t"
                         "s_waitcnt vmcnt(0)"
                         : "=&v"(v0), "=&v"(v1)
                         : "v"(pa), "v"(pa + 64) : "memory");
        } while (v0 < ta || v1 < ta);
    }
    if (tb > 0) {
        int v0, v1;
        const unsigned* pb = fb + lane;
        do {
            asm volatile("global_load_dword %0, %2, off sc0 sc1\n\t"
                         "global_load_dword %1, %3, off sc0 sc1\n\t"
                         "s_waitcnt vmcnt(0)"
                         : "=&v"(v0), "=&v"(v1)
                         : "v"(pb), "v"(pb + 64) : "memory");
        } while (v0 < tb || v1 < tb);
    }
}

__global__ __launch_bounds__(256, 1) void lstm_persist(
    const short* __restrict__ xb,    // [T][64][512] bf16
    const short* __restrict__ wp,    // packed weights
    short* __restrict__ h0r,         // [8][64][512] bf16 ring (slot s = h0[s-1])
    short* __restrict__ h1r,         // [8][64][512] bf16 ring
    const float* __restrict__ bxh,   // [2][2048]
    const float* __restrict__ bhh,   // [2][2048]
    float* __restrict__ out,         // T*B*H | hT[2,B,H] | cT[2,B,H]
    unsigned* flags) {               // [2][32 blocks][4 waves]

    const int l    = blockIdx.x >> 5;
    const int bb   = blockIdx.x & 31;
    const int tid  = threadIdx.x;
    const int wv   = tid >> 6;
    const int lane = tid & 63;

    __shared__ float red[16 * 1152];  // [wv*4+g][m:64, stride 18] (+n 16)

    // ---- weights into registers (once) ----
    s16x8 breg[4][8];
    {
        const short* wb = wp + (size_t)(blockIdx.x * 4 + wv) * 16384 + lane * 8;
        #pragma unroll
        for (int g = 0; g < 4; ++g)
            #pragma unroll
            for (int kk = 0; kk < 8; ++kk)
                breg[g][kk] = *(const s16x8*)(wb + (g * 8 + kk) * 512);
    }

    // ---- epilogue constants: thread owns (m = tid>>2, n0 = (tid&3)*4) ----
    const int em  = tid >> 2;
    const int en0 = (tid & 3) * 4;
    const int ej  = bb * 16 + en0;
    float bsum[4][4];
    #pragma unroll
    for (int g = 0; g < 4; ++g)
        #pragma unroll
        for (int c = 0; c < 4; ++c)
            bsum[g][c] = bxh[l * 2048 + g * 512 + ej + c]
                       + bhh[l * 2048 + g * 512 + ej + c];

    float creg[4] = {0.f, 0.f, 0.f, 0.f};

    const int arow = lane & 15;
    const int acol = wv * 128 + (lane >> 4) * 8;   // + kk*32 (as 64 B asm offsets)
    const int aboff = arow * 512 + acol;

    const unsigned* f0 = flags;
    const unsigned* f1 = flags + 128;
    unsigned* myflag = flags + blockIdx.x * 4 + wv;

    for (int t = 0; t < T_SEQ; ++t) {
        f32x4 acc[4][4];
        #pragma unroll
        for (int g = 0; g < 4; ++g)
            #pragma unroll
            for (int ms = 0; ms < 4; ++ms)
                acc[g][ms] = (f32x4){0.f, 0.f, 0.f, 0.f};

        i32x4 af[4][4];

        if (l == 0) {
            // input half = x[t]: no wait, normal cached loads (hides barrier)
            const short* ab = xb + (size_t)t * 32768 + aboff;
            s16x8 ax[4][4];
            #pragma unroll
            for (int ms = 0; ms < 4; ++ms)
                #pragma unroll
                for (int kk = 0; kk < 4; ++kk)
                    ax[ms][kk] = *(const s16x8*)(ab + ms * 8192 + kk * 32);
            #pragma unroll
            for (int kk = 0; kk < 4; ++kk)
                #pragma unroll
                for (int g = 0; g < 4; ++g)
                    #pragma unroll
                    for (int ms = 0; ms < 4; ++ms)
                        acc[g][ms] = __builtin_amdgcn_mfma_f32_16x16x32_bf16(
                            ax[ms][kk], breg[g][kk], acc[g][ms], 0, 0, 0);
            // wait: own domain >= t, l1 backpressure >= t-7
            waitf(f0, t, f1, t - 7, lane);
            // recurrent half = h0[t-1] (slot t&7), coherent loads
            load16_c(af, h0r + (size_t)(t & 7) * 32768 + aboff);
            #pragma unroll
            for (int kk = 0; kk < 4; ++kk)
                #pragma unroll
                for (int g = 0; g < 4; ++g)
                    #pragma unroll
                    for (int ms = 0; ms < 4; ++ms)
                        acc[g][ms] = __builtin_amdgcn_mfma_f32_16x16x32_bf16(
                            __builtin_bit_cast(s16x8, af[ms][kk]),
                            breg[g][4 + kk], acc[g][ms], 0, 0, 0);
        } else {
            // recurrent half = h1[t-1]: own-domain wait (fast)
            waitf(f1, t, f1, 0, lane);
            load16_c(af, h1r + (size_t)(t & 7) * 32768 + aboff);
            #pragma unroll
            for (int kk = 0; kk < 4; ++kk)
                #pragma unroll
                for (int g = 0; g < 4; ++g)
                    #pragma unroll
                    for (int ms = 0; ms < 4; ++ms)
                        acc[g][ms] = __builtin_amdgcn_mfma_f32_16x16x32_bf16(
                            __builtin_bit_cast(s16x8, af[ms][kk]),
                            breg[g][4 + kk], acc[g][ms], 0, 0, 0);
            // input half = h0[t] (slot (t+1)&7): wait l0 published round t
            waitf(f0, t + 1, f0, 0, lane);
            load16_c(af, h0r + (size_t)((t + 1) & 7) * 32768 + aboff);
            #pragma unroll
            for (int kk = 0; kk < 4; ++kk)
                #pragma unroll
                for (int g = 0; g < 4; ++g)
                    #pragma unroll
                    for (int ms = 0; ms < 4; ++ms)
                        acc[g][ms] = __builtin_amdgcn_mfma_f32_16x16x32_bf16(
                            __builtin_bit_cast(s16x8, af[ms][kk]),
                            breg[g][kk], acc[g][ms], 0, 0, 0);
        }

        // ---- cross-wave K-reduction (stride 18 -> 2-way banks, free) ----
        #pragma unroll
        for (int g = 0; g < 4; ++g)
            #pragma unroll
            for (int ms = 0; ms < 4; ++ms)
                #pragma unroll
                for (int q = 0; q < 4; ++q)
                    red[(wv * 4 + g) * 1152
                        + (ms * 16 + (lane >> 4) * 4 + q) * 18 + arow] = acc[g][ms][q];
        __syncthreads();

        // ---- epilogue: 4 cells (em, en0..en0+3) ----
        float cg[4][4];
        #pragma unroll
        for (int g = 0; g < 4; ++g)
            #pragma unroll
            for (int c = 0; c < 4; ++c)
                cg[g][c] = bsum[g][c];
        #pragma unroll
        for (int w = 0; w < 4; ++w)
            #pragma unroll
            for (int g = 0; g < 4; ++g) {
                const float* rp = &red[(w * 4 + g) * 1152 + em * 18 + en0];
                float2 p0 = *(const float2*)rp;
                float2 p1 = *(const float2*)(rp + 2);
                cg[g][0] += p0.x; cg[g][1] += p0.y;
                cg[g][2] += p1.x; cg[g][3] += p1.y;
            }

        float hv[4];
        #pragma unroll
        for (int c = 0; c < 4; ++c) {
            float cn = sigf(cg[1][c]) * creg[c] + sigf(cg[0][c]) * tanhff(cg[2][c]);
            hv[c] = sigf(cg[3][c]) * tanhff(cn);
            creg[c] = cn;
        }

        // h ring store (coherent, write-through to L3)
        {
            short* hring = (l == 0) ? h0r : h1r;
            short* hp = hring + (size_t)((t + 1) & 7) * 32768 + em * 512 + ej;
            unsigned b0 = (unsigned)(unsigned short)f2bf(hv[0])
                        | ((unsigned)(unsigned short)f2bf(hv[1]) << 16);
            unsigned b1 = (unsigned)(unsigned short)f2bf(hv[2])
                        | ((unsigned)(unsigned short)f2bf(hv[3]) << 16);
            i32x2 hv2 = {(int)b0, (int)b1};
            asm volatile("global_store_dwordx2 %0, %1, off sc0 sc1"
                         :: "v"(hp), "v"(hv2) : "memory");
        }
        // normal cached output stores
        if (l == 1) {
            float4 o = {hv[0], hv[1], hv[2], hv[3]};
            *(float4*)(out + (size_t)t * 32768 + (size_t)em * 512 + ej) = o;
        }
        if (t == T_SEQ - 1) {
            size_t base = (size_t)T_SEQ * 32768;
            float4 oh = {hv[0], hv[1], hv[2], hv[3]};
            float4 oc = {creg[0], creg[1], creg[2], creg[3]};
            *(float4*)(out + base + (size_t)(l * 64 + em) * 512 + ej) = oh;
            *(float4*)(out + base + 65536 + (size_t)(l * 64 + em) * 512 + ej) = oc;
        }

        // drain sc1 stores, then publish per-wave flag (single writer)
        asm volatile("s_waitcnt vmcnt(0)" ::: "memory");
        if (lane == 0) {
            int fv = t + 1;
            asm volatile("global_store_dword %0, %1, off sc0 sc1"
                         :: "v"(myflag), "v"(fv) : "memory");
        }
    }
}

extern "C" void kernel_launch(void* const* d_in, const int* in_sizes, int n_in,
                              void* d_out, int out_size, void* d_ws, size_t ws_size,
                              hipStream_t stream) {
    const float* x   = (const float*)d_in[0];
    const float* Wxh = (const float*)d_in[1];
    const float* Whh = (const float*)d_in[2];
    const float* bxh = (const float*)d_in[3];
    const float* bhh = (const float*)d_in[4];
    float* out = (float*)d_out;

    char* ws = (char*)d_ws;
    short*    xb    = (short*)(ws);                     // 33,554,432 B
    short*    wpk   = (short*)(ws + 33554432);          //  8,388,608 B
    short*    h0r   = (short*)(ws + 41943040);          //    524,288 B
    short*    h1r   = (short*)(ws + 42467328);          //    524,288 B
    unsigned* flags = (unsigned*)(ws + 42991616);       //      1,024 B

    // zero rings + flags (ws re-poisoned 0xAA before every timed launch)
    hipMemsetAsync(ws + 41943040, 0, 1049600, stream);

    xcast_kernel<<<dim3(8192), dim3(256), 0, stream>>>(x, xb);
    wpack_kernel<<<dim3(2048), dim3(256), 0, stream>>>(Wxh, Whh, wpk);

    lstm_persist<<<dim3(64), dim3(256), 0, stream>>>(xb, wpk, h0r, h1r,
                                                     bxh, bhh, out, flags);
}